// Round 5
// baseline (214.803 us; speedup 1.0000x reference)
//
#include <hip/hip_runtime.h>

#define NN 40000
#define NE 640000
#define DD 128
#define CAP 64

typedef __attribute__((ext_vector_type(8))) short short8;
typedef __attribute__((ext_vector_type(4))) float floatx4;

__device__ __forceinline__ unsigned short f2bf(float f) {
    union { float f; unsigned u; } v; v.f = f;
    return (unsigned short)((v.u + 0x7fffu + ((v.u >> 16) & 1u)) >> 16);
}
__device__ __forceinline__ float bflo2f(unsigned u) {
    union { unsigned u; float f; } v; v.u = u << 16; return v.f;
}
__device__ __forceinline__ float bfhi2f(unsigned u) {
    union { unsigned u; float f; } v; v.u = u & 0xffff0000u; return v.f;
}

// ws layout (kernel_launch): xb[NN*DD]bf16 | h[NN*DD]bf16 | W1b | W2b | stats[256]f32 | cnt[NN] | eidx[NN*CAP]

// One pass: bucket edges (order-free), convert x/W1/W2 to bf16.
// eidx writes go through non-returning atomicExch so they resolve at the
// memory-side LLC like the cnt atomics — avoids cross-XCD partial-line
// write-back amplification seen in round 4 (WRITE_SIZE 49 MB for a 10 MB table).
__global__ void k_prep(const float* __restrict__ x, const int* __restrict__ src,
                       const int* __restrict__ dst, const float* __restrict__ W1,
                       const float* __restrict__ W2, unsigned short* __restrict__ xb,
                       unsigned short* __restrict__ W1b, unsigned short* __restrict__ W2b,
                       int* __restrict__ cnt, int* __restrict__ eidx) {
    const int tid = blockIdx.x * 256 + threadIdx.x;
    const int P = gridDim.x * 256;
    if (tid < NE) {
        int d = dst[tid];
        int slot = atomicAdd(&cnt[d], 1);
        if (slot < CAP) atomicExch(&eidx[d * CAP + slot], src[tid]);
    }
    const float4* x4 = (const float4*)x;
    for (int i = tid; i < NN * DD / 4; i += P) {
        float4 v = x4[i];
        ushort4 o;
        o.x = f2bf(v.x); o.y = f2bf(v.y); o.z = f2bf(v.z); o.w = f2bf(v.w);
        ((ushort4*)xb)[i] = o;
    }
    if (tid < 8192) {
        const float4* w4 = (tid < 4096) ? (const float4*)W1 : (const float4*)W2;
        unsigned short* wb = (tid < 4096) ? W1b : W2b;
        int i = tid & 4095;
        float4 v = w4[i];
        ushort4 o;
        o.x = f2bf(v.x); o.y = f2bf(v.y); o.z = f2bf(v.z); o.w = f2bf(v.w);
        ((ushort4*)wb)[i] = o;
    }
}

// 4 nodes per block; one 64-lane wave per node; bf16x2 (dword) per lane.
__launch_bounds__(256)
__global__ void k_gather(const unsigned short* __restrict__ xb, const int* __restrict__ eidx,
                         const int* __restrict__ cnt, const float* __restrict__ eps,
                         unsigned short* __restrict__ h) {
    const int n = blockIdx.x * 4 + (threadIdx.x >> 6);
    const int lane = threadIdx.x & 63;
    const unsigned* xw = (const unsigned*)xb;
    const float s = 1.0f + eps[0];
    unsigned xv = xw[n * 64 + lane];
    float ax = bflo2f(xv) * s, ay = bfhi2f(xv) * s;
    int deg = cnt[n];
    deg = (deg > CAP) ? CAP : deg;
    const int* row = eidx + n * CAP;
    int j = 0;
    for (; j + 3 < deg; j += 4) {
        int s0 = row[j], s1 = row[j + 1], s2 = row[j + 2], s3 = row[j + 3];
        unsigned v0 = xw[s0 * 64 + lane];
        unsigned v1 = xw[s1 * 64 + lane];
        unsigned v2 = xw[s2 * 64 + lane];
        unsigned v3 = xw[s3 * 64 + lane];
        ax += (fmaxf(bflo2f(v0), 0.f) + fmaxf(bflo2f(v1), 0.f)) +
              (fmaxf(bflo2f(v2), 0.f) + fmaxf(bflo2f(v3), 0.f));
        ay += (fmaxf(bfhi2f(v0), 0.f) + fmaxf(bfhi2f(v1), 0.f)) +
              (fmaxf(bfhi2f(v2), 0.f) + fmaxf(bfhi2f(v3), 0.f));
    }
    for (; j < deg; ++j) {
        unsigned v = xw[row[j] * 64 + lane];
        ax += fmaxf(bflo2f(v), 0.f);
        ay += fmaxf(bfhi2f(v), 0.f);
    }
    ((unsigned*)h)[n * 64 + lane] = ((unsigned)f2bf(ay) << 16) | (unsigned)f2bf(ax);
}

// MFMA GEMM1: h1 = h @ W1^T + b1, fused BN-stats. Wave = 16 rows, block = 64 rows.
__launch_bounds__(256)
__global__ void k_gemm1(const unsigned short* __restrict__ h,
                        const unsigned short* __restrict__ W1b,
                        const float* __restrict__ b1,
                        float* __restrict__ h1, float* __restrict__ stats) {
    __shared__ float red[2][4][DD];
    const int t = threadIdx.x;
    const int wv = t >> 6, lane = t & 63, m = lane & 15, q = lane >> 4;
    const int r0 = blockIdx.x * 64 + wv * 16;
    floatx4 acc[8];
    #pragma unroll
    for (int nt = 0; nt < 8; ++nt) acc[nt] = (floatx4){0.f, 0.f, 0.f, 0.f};
    const unsigned short* arow = h + (r0 + m) * DD + q * 8;
    const unsigned short* brow = W1b + m * DD + q * 8;
    #pragma unroll
    for (int kt = 0; kt < 4; ++kt) {
        short8 a = *(const short8*)(arow + kt * 32);
        #pragma unroll
        for (int nt = 0; nt < 8; ++nt) {
            short8 b = *(const short8*)(brow + nt * 16 * DD + kt * 32);
            acc[nt] = __builtin_amdgcn_mfma_f32_16x16x32_bf16(a, b, acc[nt], 0, 0, 0);
        }
    }
    #pragma unroll
    for (int nt = 0; nt < 8; ++nt) {
        float bv = b1[nt * 16 + m];
        float cs = 0.f, cq = 0.f;
        #pragma unroll
        for (int r = 0; r < 4; ++r) {
            float v = acc[nt][r] + bv;
            h1[(r0 + q * 4 + r) * DD + nt * 16 + m] = v;
            cs += v;
            cq = fmaf(v, v, cq);
        }
        cs += __shfl_xor(cs, 16); cs += __shfl_xor(cs, 32);
        cq += __shfl_xor(cq, 16); cq += __shfl_xor(cq, 32);
        if (q == 0) { red[0][wv][nt * 16 + m] = cs; red[1][wv][nt * 16 + m] = cq; }
    }
    __syncthreads();
    {
        int plane = t >> 7, j = t & 127;
        float v = (red[plane][0][j] + red[plane][1][j]) + (red[plane][2][j] + red[plane][3][j]);
        atomicAdd(stats + plane * DD + j, v);
    }
}

// MFMA GEMM2 (in-place over h1): BN affine + ReLU fused into A-fragment build.
__launch_bounds__(256)
__global__ void k_gemm2(float* __restrict__ io, const unsigned short* __restrict__ W2b,
                        const float* __restrict__ b2, const float* __restrict__ stats,
                        const float* __restrict__ gamma, const float* __restrict__ beta) {
    __shared__ float ssc[DD], ssh[DD];
    const int t = threadIdx.x;
    if (t < DD) {
        const float inv_n = 1.0f / (float)NN;
        float mu = stats[t] * inv_n;
        float var = stats[DD + t] * inv_n - mu * mu;
        float sc = rsqrtf(var + 1e-5f) * gamma[t];
        ssc[t] = sc;
        ssh[t] = beta[t] - mu * sc;
    }
    __syncthreads();
    const int wv = t >> 6, lane = t & 63, m = lane & 15, q = lane >> 4;
    const int r0 = blockIdx.x * 64 + wv * 16;
    floatx4 acc[8];
    #pragma unroll
    for (int nt = 0; nt < 8; ++nt) acc[nt] = (floatx4){0.f, 0.f, 0.f, 0.f};
    const float* arow = io + (r0 + m) * DD + q * 8;
    const unsigned short* brow = W2b + m * DD + q * 8;
    #pragma unroll
    for (int kt = 0; kt < 4; ++kt) {
        const float* ap = arow + kt * 32;
        const int k0 = kt * 32 + q * 8;
        float4 v0 = *(const float4*)(ap);
        float4 v1 = *(const float4*)(ap + 4);
        float4 c0 = *(const float4*)(ssc + k0);
        float4 c1 = *(const float4*)(ssc + k0 + 4);
        float4 d0 = *(const float4*)(ssh + k0);
        float4 d1 = *(const float4*)(ssh + k0 + 4);
        short8 a;
        a[0] = (short)f2bf(fmaxf(fmaf(v0.x, c0.x, d0.x), 0.f));
        a[1] = (short)f2bf(fmaxf(fmaf(v0.y, c0.y, d0.y), 0.f));
        a[2] = (short)f2bf(fmaxf(fmaf(v0.z, c0.z, d0.z), 0.f));
        a[3] = (short)f2bf(fmaxf(fmaf(v0.w, c0.w, d0.w), 0.f));
        a[4] = (short)f2bf(fmaxf(fmaf(v1.x, c1.x, d1.x), 0.f));
        a[5] = (short)f2bf(fmaxf(fmaf(v1.y, c1.y, d1.y), 0.f));
        a[6] = (short)f2bf(fmaxf(fmaf(v1.z, c1.z, d1.z), 0.f));
        a[7] = (short)f2bf(fmaxf(fmaf(v1.w, c1.w, d1.w), 0.f));
        #pragma unroll
        for (int nt = 0; nt < 8; ++nt) {
            short8 b = *(const short8*)(brow + nt * 16 * DD + kt * 32);
            acc[nt] = __builtin_amdgcn_mfma_f32_16x16x32_bf16(a, b, acc[nt], 0, 0, 0);
        }
    }
    #pragma unroll
    for (int nt = 0; nt < 8; ++nt) {
        float bv = b2[nt * 16 + m];
        #pragma unroll
        for (int r = 0; r < 4; ++r)
            io[(r0 + q * 4 + r) * DD + nt * 16 + m] = acc[nt][r] + bv;
    }
}

extern "C" void kernel_launch(void* const* d_in, const int* in_sizes, int n_in,
                              void* d_out, int out_size, void* d_ws, size_t ws_size,
                              hipStream_t stream) {
    const float* x     = (const float*)d_in[0];
    const int*   src   = (const int*)d_in[1];
    const int*   dst   = (const int*)d_in[2];
    const float* W1    = (const float*)d_in[3];
    const float* b1    = (const float*)d_in[4];
    const float* gamma = (const float*)d_in[5];
    const float* beta  = (const float*)d_in[6];
    const float* W2    = (const float*)d_in[7];
    const float* b2    = (const float*)d_in[8];
    const float* eps   = (const float*)d_in[9];
    float* out = (float*)d_out;

    unsigned short* xb  = (unsigned short*)d_ws;       // NN*DD bf16
    unsigned short* h   = xb + NN * DD;                // NN*DD bf16
    unsigned short* W1b = h + NN * DD;                 // DD*DD bf16
    unsigned short* W2b = W1b + DD * DD;               // DD*DD bf16
    float* stats = (float*)(W2b + DD * DD);            // 256 f32
    int*   cnt   = (int*)(stats + 256);                // NN
    int*   eidx  = cnt + NN;                           // NN*CAP

    // zero stats + cnt in one memset (they are contiguous)
    hipMemsetAsync(stats, 0, (256 + NN) * sizeof(int), stream);
    hipLaunchKernelGGL(k_prep,   dim3(2560),    dim3(256), 0, stream,
                       x, src, dst, W1, W2, xb, W1b, W2b, cnt, eidx);
    hipLaunchKernelGGL(k_gather, dim3(NN / 4),  dim3(256), 0, stream,
                       xb, eidx, cnt, eps, h);
    hipLaunchKernelGGL(k_gemm1,  dim3(NN / 64), dim3(256), 0, stream,
                       h, W1b, b1, out, stats);
    hipLaunchKernelGGL(k_gemm2,  dim3(NN / 64), dim3(256), 0, stream,
                       out, W2b, b2, stats, gamma, beta);
}

// Round 6
// 195.277 us; speedup vs baseline: 1.1000x; 1.1000x over previous
//
#include <hip/hip_runtime.h>

#define NN 40000
#define NE 640000
#define DD 128
#define CAP 64

typedef __attribute__((ext_vector_type(8))) short short8;
typedef __attribute__((ext_vector_type(4))) float floatx4;

__device__ __forceinline__ unsigned short f2bf(float f) {
    union { float f; unsigned u; } v; v.f = f;
    return (unsigned short)((v.u + 0x7fffu + ((v.u >> 16) & 1u)) >> 16);
}
__device__ __forceinline__ float bflo2f(unsigned u) {
    union { unsigned u; float f; } v; v.u = u << 16; return v.f;
}
__device__ __forceinline__ float bfhi2f(unsigned u) {
    union { unsigned u; float f; } v; v.u = u & 0xffff0000u; return v.f;
}

// ws layout (kernel_launch): xb[NN*DD]bf16 | h[NN*DD]bf16 | W1b | W2b | stats[256]f32 | cnt[NN]i32 | eidx[NN*CAP]u16

__global__ void k_convert(const float* __restrict__ x, const float* __restrict__ W1,
                          const float* __restrict__ W2, unsigned short* __restrict__ xb,
                          unsigned short* __restrict__ W1b, unsigned short* __restrict__ W2b) {
    const int tid = blockIdx.x * 256 + threadIdx.x;
    const int P = gridDim.x * 256;
    const float4* x4 = (const float4*)x;
    for (int i = tid; i < NN * DD / 4; i += P) {
        float4 v = x4[i];
        ushort4 o;
        o.x = f2bf(v.x); o.y = f2bf(v.y); o.z = f2bf(v.z); o.w = f2bf(v.w);
        ((ushort4*)xb)[i] = o;
    }
    if (tid < 8192) {
        const float4* w4 = (tid < 4096) ? (const float4*)W1 : (const float4*)W2;
        unsigned short* wb = (tid < 4096) ? W1b : W2b;
        int i = tid & 4095;
        float4 v = w4[i];
        ushort4 o;
        o.x = f2bf(v.x); o.y = f2bf(v.y); o.z = f2bf(v.z); o.w = f2bf(v.w);
        ((ushort4*)wb)[i] = o;
    }
}

// Bucket edges by dst (order-free). Node ids fit in uint16.
__global__ void k_bucket(const int* __restrict__ src, const int* __restrict__ dst,
                         int* __restrict__ cnt, unsigned short* __restrict__ eidx) {
    const int e = blockIdx.x * 256 + threadIdx.x;   // grid covers NE exactly
    const int d = dst[e];
    const int s = src[e];
    const int slot = atomicAdd(&cnt[d], 1);
    if (slot < CAP) eidx[d * CAP + slot] = (unsigned short)s;
}

// 4 nodes per block; one 64-lane wave per node; bf16x2 (dword) per lane.
__launch_bounds__(256)
__global__ void k_gather(const unsigned short* __restrict__ xb,
                         const unsigned short* __restrict__ eidx,
                         const int* __restrict__ cnt, const float* __restrict__ eps,
                         unsigned short* __restrict__ h) {
    const int n = blockIdx.x * 4 + (threadIdx.x >> 6);
    const int lane = threadIdx.x & 63;
    const unsigned* xw = (const unsigned*)xb;
    const float s = 1.0f + eps[0];
    unsigned xv = xw[n * 64 + lane];
    float ax = bflo2f(xv) * s, ay = bfhi2f(xv) * s;
    int deg = cnt[n];
    deg = (deg > CAP) ? CAP : deg;
    const unsigned short* row = eidx + n * CAP;
    int j = 0;
    for (; j + 3 < deg; j += 4) {
        ushort4 s4 = *(const ushort4*)(row + j);      // row 128B-aligned, j%4==0
        unsigned v0 = xw[(int)s4.x * 64 + lane];
        unsigned v1 = xw[(int)s4.y * 64 + lane];
        unsigned v2 = xw[(int)s4.z * 64 + lane];
        unsigned v3 = xw[(int)s4.w * 64 + lane];
        ax += (fmaxf(bflo2f(v0), 0.f) + fmaxf(bflo2f(v1), 0.f)) +
              (fmaxf(bflo2f(v2), 0.f) + fmaxf(bflo2f(v3), 0.f));
        ay += (fmaxf(bfhi2f(v0), 0.f) + fmaxf(bfhi2f(v1), 0.f)) +
              (fmaxf(bfhi2f(v2), 0.f) + fmaxf(bfhi2f(v3), 0.f));
    }
    for (; j < deg; ++j) {
        unsigned v = xw[(int)row[j] * 64 + lane];
        ax += fmaxf(bflo2f(v), 0.f);
        ay += fmaxf(bfhi2f(v), 0.f);
    }
    ((unsigned*)h)[n * 64 + lane] = ((unsigned)f2bf(ay) << 16) | (unsigned)f2bf(ax);
}

// MFMA GEMM1: h1 = h @ W1^T + b1, fused BN-stats. Wave = 16 rows, block = 64 rows.
__launch_bounds__(256)
__global__ void k_gemm1(const unsigned short* __restrict__ h,
                        const unsigned short* __restrict__ W1b,
                        const float* __restrict__ b1,
                        float* __restrict__ h1, float* __restrict__ stats) {
    __shared__ float red[2][4][DD];
    const int t = threadIdx.x;
    const int wv = t >> 6, lane = t & 63, m = lane & 15, q = lane >> 4;
    const int r0 = blockIdx.x * 64 + wv * 16;
    floatx4 acc[8];
    #pragma unroll
    for (int nt = 0; nt < 8; ++nt) acc[nt] = (floatx4){0.f, 0.f, 0.f, 0.f};
    const unsigned short* arow = h + (r0 + m) * DD + q * 8;
    const unsigned short* brow = W1b + m * DD + q * 8;
    #pragma unroll
    for (int kt = 0; kt < 4; ++kt) {
        short8 a = *(const short8*)(arow + kt * 32);
        #pragma unroll
        for (int nt = 0; nt < 8; ++nt) {
            short8 b = *(const short8*)(brow + nt * 16 * DD + kt * 32);
            acc[nt] = __builtin_amdgcn_mfma_f32_16x16x32_bf16(a, b, acc[nt], 0, 0, 0);
        }
    }
    #pragma unroll
    for (int nt = 0; nt < 8; ++nt) {
        float bv = b1[nt * 16 + m];
        float cs = 0.f, cq = 0.f;
        #pragma unroll
        for (int r = 0; r < 4; ++r) {
            float v = acc[nt][r] + bv;
            h1[(r0 + q * 4 + r) * DD + nt * 16 + m] = v;
            cs += v;
            cq = fmaf(v, v, cq);
        }
        cs += __shfl_xor(cs, 16); cs += __shfl_xor(cs, 32);
        cq += __shfl_xor(cq, 16); cq += __shfl_xor(cq, 32);
        if (q == 0) { red[0][wv][nt * 16 + m] = cs; red[1][wv][nt * 16 + m] = cq; }
    }
    __syncthreads();
    {
        int plane = t >> 7, j = t & 127;
        float v = (red[plane][0][j] + red[plane][1][j]) + (red[plane][2][j] + red[plane][3][j]);
        atomicAdd(stats + plane * DD + j, v);
    }
}

// MFMA GEMM2 (in-place over h1): BN affine + ReLU fused into A-fragment build.
__launch_bounds__(256)
__global__ void k_gemm2(float* __restrict__ io, const unsigned short* __restrict__ W2b,
                        const float* __restrict__ b2, const float* __restrict__ stats,
                        const float* __restrict__ gamma, const float* __restrict__ beta) {
    __shared__ float ssc[DD], ssh[DD];
    const int t = threadIdx.x;
    if (t < DD) {
        const float inv_n = 1.0f / (float)NN;
        float mu = stats[t] * inv_n;
        float var = stats[DD + t] * inv_n - mu * mu;
        float sc = rsqrtf(var + 1e-5f) * gamma[t];
        ssc[t] = sc;
        ssh[t] = beta[t] - mu * sc;
    }
    __syncthreads();
    const int wv = t >> 6, lane = t & 63, m = lane & 15, q = lane >> 4;
    const int r0 = blockIdx.x * 64 + wv * 16;
    floatx4 acc[8];
    #pragma unroll
    for (int nt = 0; nt < 8; ++nt) acc[nt] = (floatx4){0.f, 0.f, 0.f, 0.f};
    const float* arow = io + (r0 + m) * DD + q * 8;
    const unsigned short* brow = W2b + m * DD + q * 8;
    #pragma unroll
    for (int kt = 0; kt < 4; ++kt) {
        const float* ap = arow + kt * 32;
        const int k0 = kt * 32 + q * 8;
        float4 v0 = *(const float4*)(ap);
        float4 v1 = *(const float4*)(ap + 4);
        float4 c0 = *(const float4*)(ssc + k0);
        float4 c1 = *(const float4*)(ssc + k0 + 4);
        float4 d0 = *(const float4*)(ssh + k0);
        float4 d1 = *(const float4*)(ssh + k0 + 4);
        short8 a;
        a[0] = (short)f2bf(fmaxf(fmaf(v0.x, c0.x, d0.x), 0.f));
        a[1] = (short)f2bf(fmaxf(fmaf(v0.y, c0.y, d0.y), 0.f));
        a[2] = (short)f2bf(fmaxf(fmaf(v0.z, c0.z, d0.z), 0.f));
        a[3] = (short)f2bf(fmaxf(fmaf(v0.w, c0.w, d0.w), 0.f));
        a[4] = (short)f2bf(fmaxf(fmaf(v1.x, c1.x, d1.x), 0.f));
        a[5] = (short)f2bf(fmaxf(fmaf(v1.y, c1.y, d1.y), 0.f));
        a[6] = (short)f2bf(fmaxf(fmaf(v1.z, c1.z, d1.z), 0.f));
        a[7] = (short)f2bf(fmaxf(fmaf(v1.w, c1.w, d1.w), 0.f));
        #pragma unroll
        for (int nt = 0; nt < 8; ++nt) {
            short8 b = *(const short8*)(brow + nt * 16 * DD + kt * 32);
            acc[nt] = __builtin_amdgcn_mfma_f32_16x16x32_bf16(a, b, acc[nt], 0, 0, 0);
        }
    }
    #pragma unroll
    for (int nt = 0; nt < 8; ++nt) {
        float bv = b2[nt * 16 + m];
        #pragma unroll
        for (int r = 0; r < 4; ++r)
            io[(r0 + q * 4 + r) * DD + nt * 16 + m] = acc[nt][r] + bv;
    }
}

extern "C" void kernel_launch(void* const* d_in, const int* in_sizes, int n_in,
                              void* d_out, int out_size, void* d_ws, size_t ws_size,
                              hipStream_t stream) {
    const float* x     = (const float*)d_in[0];
    const int*   src   = (const int*)d_in[1];
    const int*   dst   = (const int*)d_in[2];
    const float* W1    = (const float*)d_in[3];
    const float* b1    = (const float*)d_in[4];
    const float* gamma = (const float*)d_in[5];
    const float* beta  = (const float*)d_in[6];
    const float* W2    = (const float*)d_in[7];
    const float* b2    = (const float*)d_in[8];
    const float* eps   = (const float*)d_in[9];
    float* out = (float*)d_out;

    unsigned short* xb  = (unsigned short*)d_ws;       // NN*DD bf16
    unsigned short* h   = xb + NN * DD;                // NN*DD bf16
    unsigned short* W1b = h + NN * DD;                 // DD*DD bf16
    unsigned short* W2b = W1b + DD * DD;               // DD*DD bf16
    float* stats = (float*)(W2b + DD * DD);            // 256 f32
    int*   cnt   = (int*)(stats + 256);                // NN i32
    unsigned short* eidx = (unsigned short*)(cnt + NN); // NN*CAP u16

    // zero stats + cnt in one memset (contiguous)
    hipMemsetAsync(stats, 0, (256 + NN) * sizeof(int), stream);
    hipLaunchKernelGGL(k_convert, dim3(1280),     dim3(256), 0, stream,
                       x, W1, W2, xb, W1b, W2b);
    hipLaunchKernelGGL(k_bucket,  dim3(NE / 256), dim3(256), 0, stream,
                       src, dst, cnt, eidx);
    hipLaunchKernelGGL(k_gather,  dim3(NN / 4),   dim3(256), 0, stream,
                       xb, eidx, cnt, eps, h);
    hipLaunchKernelGGL(k_gemm1,   dim3(NN / 64),  dim3(256), 0, stream,
                       h, W1b, b1, out, stats);
    hipLaunchKernelGGL(k_gemm2,   dim3(NN / 64),  dim3(256), 0, stream,
                       out, W2b, b2, stats, gamma, beta);
}

// Round 7
// 193.808 us; speedup vs baseline: 1.1083x; 1.0076x over previous
//
#include <hip/hip_runtime.h>

#define NN 40000
#define NE 640000
#define DD 128
#define CAP 64
#define NRANK 312   // edge slices; grid = 8 * NRANK

typedef __attribute__((ext_vector_type(8))) short short8;
typedef __attribute__((ext_vector_type(4))) float floatx4;

__device__ __forceinline__ unsigned short f2bf(float f) {
    union { float f; unsigned u; } v; v.f = f;
    return (unsigned short)((v.u + 0x7fffu + ((v.u >> 16) & 1u)) >> 16);
}
__device__ __forceinline__ float bflo2f(unsigned u) {
    union { unsigned u; float f; } v; v.u = u << 16; return v.f;
}
__device__ __forceinline__ float bfhi2f(unsigned u) {
    union { unsigned u; float f; } v; v.u = u & 0xffff0000u; return v.f;
}

// ws layout: xb[NN*DD]bf16 | h[NN*DD]bf16 | W1b | W2b | stats[256]f32 | cnt[NN]i32 | eidx[NN*CAP]u16

// Convert x/W1/W2 to bf16; zero stats+cnt (replaces memset dispatch).
__global__ void k_convert(const float* __restrict__ x, const float* __restrict__ W1,
                          const float* __restrict__ W2, unsigned short* __restrict__ xb,
                          unsigned short* __restrict__ W1b, unsigned short* __restrict__ W2b,
                          int* __restrict__ zbase) {
    const int tid = blockIdx.x * 256 + threadIdx.x;
    const int P = gridDim.x * 256;
    for (int i = tid; i < 256 + NN; i += P) zbase[i] = 0;   // stats + cnt (contiguous)
    const float4* x4 = (const float4*)x;
    for (int i = tid; i < NN * DD / 4; i += P) {
        float4 v = x4[i];
        ushort4 o;
        o.x = f2bf(v.x); o.y = f2bf(v.y); o.z = f2bf(v.z); o.w = f2bf(v.w);
        ((ushort4*)xb)[i] = o;
    }
    if (tid < 8192) {
        const float4* w4 = (tid < 4096) ? (const float4*)W1 : (const float4*)W2;
        unsigned short* wb = (tid < 4096) ? W1b : W2b;
        int i = tid & 4095;
        float4 v = w4[i];
        ushort4 o;
        o.x = f2bf(v.x); o.y = f2bf(v.y); o.z = f2bf(v.z); o.w = f2bf(v.w);
        ((ushort4*)wb)[i] = o;
    }
}

// XCD-partitioned bucketing: blockIdx&7 selects the XCD (round-robin dispatch
// heuristic); each XCD only processes edges whose dst lies in its 5000-node
// range, so every cnt/eidx cache line is dirtied by exactly one XCD's L2 —
// kills the 8x write-allocate duplication measured in rounds 4/5 (49 MB
// writeback for a 10 MB table). 8 blocks (one per XCD) scan each edge slice.
__global__ void k_bucket(const int* __restrict__ src, const int* __restrict__ dst,
                         int* __restrict__ cnt, unsigned short* __restrict__ eidx) {
    const int xcd = blockIdx.x & 7;
    const int rank = blockIdx.x >> 3;                  // 0..NRANK-1
    const int e0 = (int)((long long)rank * NE / NRANK);
    const int e1 = (int)((long long)(rank + 1) * NE / NRANK);
    const int lo = xcd * (NN / 8);
    for (int e = e0 + (int)threadIdx.x; e < e1; e += 256) {
        int d = dst[e];
        if ((unsigned)(d - lo) < (unsigned)(NN / 8)) {
            int slot = atomicAdd(&cnt[d], 1);
            if (slot < CAP) eidx[d * CAP + slot] = (unsigned short)src[e];
        }
    }
}

// Gather: 2 nodes per wave (32 lanes x 8B each) — half the load-instruction
// count of the 64-lane/node version, twice the rows in flight.
__launch_bounds__(256)
__global__ void k_gather(const unsigned short* __restrict__ xb,
                         const unsigned short* __restrict__ eidx,
                         const int* __restrict__ cnt, const float* __restrict__ eps,
                         unsigned short* __restrict__ h) {
    const int t = threadIdx.x;
    const int ln = t & 31;
    const int n = blockIdx.x * 8 + (t >> 5);
    const uint2* xw = (const uint2*)xb;
    const float s = 1.0f + eps[0];
    uint2 xv = xw[n * 32 + ln];
    float a0 = bflo2f(xv.x) * s, a1 = bfhi2f(xv.x) * s;
    float a2 = bflo2f(xv.y) * s, a3 = bfhi2f(xv.y) * s;
    int deg = cnt[n];
    deg = (deg > CAP) ? CAP : deg;
    const unsigned short* row = eidx + n * CAP;
    int j = 0;
    for (; j + 3 < deg; j += 4) {
        ushort4 s4 = *(const ushort4*)(row + j);
        uint2 v0 = xw[(int)s4.x * 32 + ln];
        uint2 v1 = xw[(int)s4.y * 32 + ln];
        uint2 v2 = xw[(int)s4.z * 32 + ln];
        uint2 v3 = xw[(int)s4.w * 32 + ln];
        a0 += (fmaxf(bflo2f(v0.x), 0.f) + fmaxf(bflo2f(v1.x), 0.f)) +
              (fmaxf(bflo2f(v2.x), 0.f) + fmaxf(bflo2f(v3.x), 0.f));
        a1 += (fmaxf(bfhi2f(v0.x), 0.f) + fmaxf(bfhi2f(v1.x), 0.f)) +
              (fmaxf(bfhi2f(v2.x), 0.f) + fmaxf(bfhi2f(v3.x), 0.f));
        a2 += (fmaxf(bflo2f(v0.y), 0.f) + fmaxf(bflo2f(v1.y), 0.f)) +
              (fmaxf(bflo2f(v2.y), 0.f) + fmaxf(bflo2f(v3.y), 0.f));
        a3 += (fmaxf(bfhi2f(v0.y), 0.f) + fmaxf(bfhi2f(v1.y), 0.f)) +
              (fmaxf(bfhi2f(v2.y), 0.f) + fmaxf(bfhi2f(v3.y), 0.f));
    }
    for (; j < deg; ++j) {
        uint2 v = xw[(int)row[j] * 32 + ln];
        a0 += fmaxf(bflo2f(v.x), 0.f);
        a1 += fmaxf(bfhi2f(v.x), 0.f);
        a2 += fmaxf(bflo2f(v.y), 0.f);
        a3 += fmaxf(bfhi2f(v.y), 0.f);
    }
    uint2 o;
    o.x = ((unsigned)f2bf(a1) << 16) | (unsigned)f2bf(a0);
    o.y = ((unsigned)f2bf(a3) << 16) | (unsigned)f2bf(a2);
    ((uint2*)h)[n * 32 + ln] = o;
}

// MFMA GEMM1: h1 = h @ W1^T + b1, fused BN-stats. Wave = 16 rows, block = 64 rows.
__launch_bounds__(256)
__global__ void k_gemm1(const unsigned short* __restrict__ h,
                        const unsigned short* __restrict__ W1b,
                        const float* __restrict__ b1,
                        float* __restrict__ h1, float* __restrict__ stats) {
    __shared__ float red[2][4][DD];
    const int t = threadIdx.x;
    const int wv = t >> 6, lane = t & 63, m = lane & 15, q = lane >> 4;
    const int r0 = blockIdx.x * 64 + wv * 16;
    floatx4 acc[8];
    #pragma unroll
    for (int nt = 0; nt < 8; ++nt) acc[nt] = (floatx4){0.f, 0.f, 0.f, 0.f};
    const unsigned short* arow = h + (r0 + m) * DD + q * 8;
    const unsigned short* brow = W1b + m * DD + q * 8;
    #pragma unroll
    for (int kt = 0; kt < 4; ++kt) {
        short8 a = *(const short8*)(arow + kt * 32);
        #pragma unroll
        for (int nt = 0; nt < 8; ++nt) {
            short8 b = *(const short8*)(brow + nt * 16 * DD + kt * 32);
            acc[nt] = __builtin_amdgcn_mfma_f32_16x16x32_bf16(a, b, acc[nt], 0, 0, 0);
        }
    }
    #pragma unroll
    for (int nt = 0; nt < 8; ++nt) {
        float bv = b1[nt * 16 + m];
        float cs = 0.f, cq = 0.f;
        #pragma unroll
        for (int r = 0; r < 4; ++r) {
            float v = acc[nt][r] + bv;
            h1[(r0 + q * 4 + r) * DD + nt * 16 + m] = v;
            cs += v;
            cq = fmaf(v, v, cq);
        }
        cs += __shfl_xor(cs, 16); cs += __shfl_xor(cs, 32);
        cq += __shfl_xor(cq, 16); cq += __shfl_xor(cq, 32);
        if (q == 0) { red[0][wv][nt * 16 + m] = cs; red[1][wv][nt * 16 + m] = cq; }
    }
    __syncthreads();
    {
        int plane = t >> 7, j = t & 127;
        float v = (red[plane][0][j] + red[plane][1][j]) + (red[plane][2][j] + red[plane][3][j]);
        atomicAdd(stats + plane * DD + j, v);
    }
}

// MFMA GEMM2 (in-place over h1): BN affine + ReLU fused into A-fragment build.
__launch_bounds__(256)
__global__ void k_gemm2(float* __restrict__ io, const unsigned short* __restrict__ W2b,
                        const float* __restrict__ b2, const float* __restrict__ stats,
                        const float* __restrict__ gamma, const float* __restrict__ beta) {
    __shared__ float ssc[DD], ssh[DD];
    const int t = threadIdx.x;
    if (t < DD) {
        const float inv_n = 1.0f / (float)NN;
        float mu = stats[t] * inv_n;
        float var = stats[DD + t] * inv_n - mu * mu;
        float sc = rsqrtf(var + 1e-5f) * gamma[t];
        ssc[t] = sc;
        ssh[t] = beta[t] - mu * sc;
    }
    __syncthreads();
    const int wv = t >> 6, lane = t & 63, m = lane & 15, q = lane >> 4;
    const int r0 = blockIdx.x * 64 + wv * 16;
    floatx4 acc[8];
    #pragma unroll
    for (int nt = 0; nt < 8; ++nt) acc[nt] = (floatx4){0.f, 0.f, 0.f, 0.f};
    const float* arow = io + (r0 + m) * DD + q * 8;
    const unsigned short* brow = W2b + m * DD + q * 8;
    #pragma unroll
    for (int kt = 0; kt < 4; ++kt) {
        const float* ap = arow + kt * 32;
        const int k0 = kt * 32 + q * 8;
        float4 v0 = *(const float4*)(ap);
        float4 v1 = *(const float4*)(ap + 4);
        float4 c0 = *(const float4*)(ssc + k0);
        float4 c1 = *(const float4*)(ssc + k0 + 4);
        float4 d0 = *(const float4*)(ssh + k0);
        float4 d1 = *(const float4*)(ssh + k0 + 4);
        short8 a;
        a[0] = (short)f2bf(fmaxf(fmaf(v0.x, c0.x, d0.x), 0.f));
        a[1] = (short)f2bf(fmaxf(fmaf(v0.y, c0.y, d0.y), 0.f));
        a[2] = (short)f2bf(fmaxf(fmaf(v0.z, c0.z, d0.z), 0.f));
        a[3] = (short)f2bf(fmaxf(fmaf(v0.w, c0.w, d0.w), 0.f));
        a[4] = (short)f2bf(fmaxf(fmaf(v1.x, c1.x, d1.x), 0.f));
        a[5] = (short)f2bf(fmaxf(fmaf(v1.y, c1.y, d1.y), 0.f));
        a[6] = (short)f2bf(fmaxf(fmaf(v1.z, c1.z, d1.z), 0.f));
        a[7] = (short)f2bf(fmaxf(fmaf(v1.w, c1.w, d1.w), 0.f));
        #pragma unroll
        for (int nt = 0; nt < 8; ++nt) {
            short8 b = *(const short8*)(brow + nt * 16 * DD + kt * 32);
            acc[nt] = __builtin_amdgcn_mfma_f32_16x16x32_bf16(a, b, acc[nt], 0, 0, 0);
        }
    }
    #pragma unroll
    for (int nt = 0; nt < 8; ++nt) {
        float bv = b2[nt * 16 + m];
        #pragma unroll
        for (int r = 0; r < 4; ++r)
            io[(r0 + q * 4 + r) * DD + nt * 16 + m] = acc[nt][r] + bv;
    }
}

extern "C" void kernel_launch(void* const* d_in, const int* in_sizes, int n_in,
                              void* d_out, int out_size, void* d_ws, size_t ws_size,
                              hipStream_t stream) {
    const float* x     = (const float*)d_in[0];
    const int*   src   = (const int*)d_in[1];
    const int*   dst   = (const int*)d_in[2];
    const float* W1    = (const float*)d_in[3];
    const float* b1    = (const float*)d_in[4];
    const float* gamma = (const float*)d_in[5];
    const float* beta  = (const float*)d_in[6];
    const float* W2    = (const float*)d_in[7];
    const float* b2    = (const float*)d_in[8];
    const float* eps   = (const float*)d_in[9];
    float* out = (float*)d_out;

    unsigned short* xb  = (unsigned short*)d_ws;       // NN*DD bf16
    unsigned short* h   = xb + NN * DD;                // NN*DD bf16
    unsigned short* W1b = h + NN * DD;                 // DD*DD bf16
    unsigned short* W2b = W1b + DD * DD;               // DD*DD bf16
    float* stats = (float*)(W2b + DD * DD);            // 256 f32
    int*   cnt   = (int*)(stats + 256);                // NN i32
    unsigned short* eidx = (unsigned short*)(cnt + NN); // NN*CAP u16

    hipLaunchKernelGGL(k_convert, dim3(1280),      dim3(256), 0, stream,
                       x, W1, W2, xb, W1b, W2b, (int*)stats);
    hipLaunchKernelGGL(k_bucket,  dim3(8 * NRANK), dim3(256), 0, stream,
                       src, dst, cnt, eidx);
    hipLaunchKernelGGL(k_gather,  dim3(NN / 8),    dim3(256), 0, stream,
                       xb, eidx, cnt, eps, h);
    hipLaunchKernelGGL(k_gemm1,   dim3(NN / 64),   dim3(256), 0, stream,
                       h, W1b, b1, out, stats);
    hipLaunchKernelGGL(k_gemm2,   dim3(NN / 64),   dim3(256), 0, stream,
                       out, W2b, b2, stats, gamma, beta);
}